// Round 1
// baseline (1187.784 us; speedup 1.0000x reference)
//
#include <hip/hip_runtime.h>
#include <math.h>

// Problem: N=8192 rows, D=256 features, fp32. Output: scalar fp32 loss.
// out = mean_i ||v0_i - v1_i||  +  0.5 * ( mean_i log S0_i + mean_i log S1_i ) - log(N-1)
// where Sv_i = sum_{j != i} exp( -max(sqrt(max(sq_i+sq_j-2*z_i.z_j,0)), 1e-12) )

#define D_DIM 256
#define BI 64
#define BJ 64
#define BK 32
#define LDA (BI + 4)   // pad 4 floats: keeps 4-float fragments 16B-aligned for ds_read_b128

__global__ void init_ws(float* __restrict__ p, int n) {
  int i = blockIdx.x * blockDim.x + threadIdx.x;
  if (i < n) p[i] = 0.0f;
}

// One block per row (256 threads == D). Computes sq0[row], sq1[row] and
// accumulates sqrt(sum (v0-v1)^2) into align_acc.
__global__ void rownorm_align(const float* __restrict__ v0, const float* __restrict__ v1,
                              float* __restrict__ sq0, float* __restrict__ sq1,
                              float* __restrict__ align_acc) {
  __shared__ float s0[256], s1[256], s2[256];
  int row = blockIdx.x;
  int t = threadIdx.x;
  size_t idx = (size_t)row * D_DIM + t;
  float a = v0[idx], b = v1[idx];
  float df = a - b;
  s0[t] = a * a; s1[t] = b * b; s2[t] = df * df;
  __syncthreads();
  for (int off = 128; off > 0; off >>= 1) {
    if (t < off) { s0[t] += s0[t + off]; s1[t] += s1[t + off]; s2[t] += s2[t + off]; }
    __syncthreads();
  }
  if (t == 0) {
    sq0[row] = s0[0];
    sq1[row] = s1[0];
    atomicAdd(align_acc, sqrtf(s2[0]));
  }
}

// 64x64 tile of the NxN distance matrix per block. fp32 GEMM (vector ALU --
// no fp32 MFMA on CDNA4), then exp epilogue, per-row partial sums -> atomicAdd.
__global__ __launch_bounds__(256) void entropy_tile(
    const float* __restrict__ z, const float* __restrict__ sq,
    float* __restrict__ S, int n) {
  __shared__ float As[BK][LDA];
  __shared__ float Bs[BK][LDA];
  __shared__ float red[BI][17];
  const int i0 = blockIdx.x * BI;
  const int j0 = blockIdx.y * BJ;
  const int t  = threadIdx.x;
  const int tx = t & 15;        // 16 threads across j
  const int ty = t >> 4;        // 16 threads across i

  float acc[4][4] = {{0.f,0.f,0.f,0.f},{0.f,0.f,0.f,0.f},{0.f,0.f,0.f,0.f},{0.f,0.f,0.f,0.f}};

  for (int k0 = 0; k0 < D_DIM; k0 += BK) {
    // 2048 elements per tile, 256 threads -> 8 each; consecutive t reads
    // consecutive k within a row (coalesced 128B), stores transposed [k][i].
    #pragma unroll
    for (int p = 0; p < 8; ++p) {
      int m = t + p * 256;
      int i = m >> 5;        // m / 32
      int k = m & 31;
      As[k][i] = z[(size_t)(i0 + i) * D_DIM + k0 + k];
      Bs[k][i] = z[(size_t)(j0 + i) * D_DIM + k0 + k];
    }
    __syncthreads();
    #pragma unroll
    for (int kk = 0; kk < BK; ++kk) {
      float a[4], b[4];
      #pragma unroll
      for (int m = 0; m < 4; ++m) a[m] = As[kk][ty * 4 + m];   // 16B-aligned -> b128
      #pragma unroll
      for (int q = 0; q < 4; ++q) b[q] = Bs[kk][tx * 4 + q];
      #pragma unroll
      for (int m = 0; m < 4; ++m)
        #pragma unroll
        for (int q = 0; q < 4; ++q)
          acc[m][q] = fmaf(a[m], b[q], acc[m][q]);
    }
    __syncthreads();
  }

  // Epilogue: distances -> exp(-d), diag masked, per-i partial sums.
  float part[4] = {0.f, 0.f, 0.f, 0.f};
  #pragma unroll
  for (int m = 0; m < 4; ++m) {
    int gi = i0 + ty * 4 + m;
    float si = sq[gi];
    #pragma unroll
    for (int q = 0; q < 4; ++q) {
      int gj = j0 + tx * 4 + q;
      float d2 = si + sq[gj] - 2.0f * acc[m][q];
      float dist = sqrtf(fmaxf(d2, 0.0f));
      dist = fmaxf(dist, 1e-12f);
      float e = __expf(-dist);
      part[m] += (gi == gj) ? 0.0f : e;
    }
  }
  #pragma unroll
  for (int m = 0; m < 4; ++m) red[ty * 4 + m][tx] = part[m];
  __syncthreads();
  if (t < BI) {
    float s = 0.0f;
    #pragma unroll
    for (int c = 0; c < 16; ++c) s += red[t][c];
    atomicAdd(&S[i0 + t], s);
  }
}

__global__ void finalize_kernel(const float* __restrict__ S0, const float* __restrict__ S1,
                                const float* __restrict__ align_acc, float* __restrict__ out,
                                int n) {
  __shared__ float sh[256];
  int t = threadIdx.x;
  float s = 0.0f;
  for (int i = t; i < n; i += 256) s += logf(S0[i]) + logf(S1[i]);
  sh[t] = s;
  __syncthreads();
  for (int off = 128; off > 0; off >>= 1) {
    if (t < off) sh[t] += sh[t + off];
    __syncthreads();
  }
  if (t == 0) {
    float align = align_acc[0] / (float)n;
    float entropy = 0.5f * sh[0] / (float)n - logf((float)(n - 1));
    out[0] = align + entropy;
  }
}

extern "C" void kernel_launch(void* const* d_in, const int* in_sizes, int n_in,
                              void* d_out, int out_size, void* d_ws, size_t ws_size,
                              hipStream_t stream) {
  const float* v0 = (const float*)d_in[0];
  const float* v1 = (const float*)d_in[1];
  float* out = (float*)d_out;
  const int n = in_sizes[0] / D_DIM;   // 8192

  float* ws        = (float*)d_ws;
  float* sq0       = ws;               // n floats
  float* sq1       = ws + n;           // n floats
  float* S0        = ws + 2 * n;       // n floats (atomic accum, must be zeroed)
  float* S1        = ws + 3 * n;       // n floats
  float* align_acc = ws + 4 * n;       // 1 float

  // Zero S0, S1, align_acc (contiguous: 2n+1 floats). ws is poisoned 0xAA each call.
  int zcount = 2 * n + 1;
  init_ws<<<(zcount + 255) / 256, 256, 0, stream>>>(S0, zcount);

  rownorm_align<<<n, 256, 0, stream>>>(v0, v1, sq0, sq1, align_acc);

  dim3 grid(n / BI, n / BJ);   // 128 x 128
  entropy_tile<<<grid, 256, 0, stream>>>(v0, sq0, S0, n);
  entropy_tile<<<grid, 256, 0, stream>>>(v1, sq1, S1, n);

  finalize_kernel<<<1, 256, 0, stream>>>(S0, S1, align_acc, out, n);
}

// Round 2
// 483.955 us; speedup vs baseline: 2.4543x; 2.4543x over previous
//
#include <hip/hip_runtime.h>
#include <math.h>

// N=8192 rows, D=256, fp32 in, scalar fp32 out.
// out = mean_i ||v0_i-v1_i|| + 0.5*(mean_i log S0_i + mean_i log S1_i) - log(N-1)
// S_i = sum_{j!=i} exp(-max(sqrt(max(sq_i+sq_j-2*z_i.z_j,0)),1e-12))
//
// Dot products via bf16 MFMA with hi/lo split: x = hi + lo (both bf16, truncated),
// dot ~= hi.hi + hi.lo + lo.hi (3 chained mfma_f32_16x16x32_bf16). Error ~1e-5 on dist.

#define D_DIM 256

typedef short bf16x8 __attribute__((ext_vector_type(8)));
typedef float f32x4 __attribute__((ext_vector_type(4)));

// fp32x4 -> packed bf16 hi plane (truncation) + bf16 lo plane (truncated remainder).
__device__ inline void split_pack(const float4 f, uint2& hi, uint2& lo) {
  unsigned ux = __float_as_uint(f.x), uy = __float_as_uint(f.y);
  unsigned uz = __float_as_uint(f.z), uw = __float_as_uint(f.w);
  float hx = __uint_as_float(ux & 0xFFFF0000u);
  float hy = __uint_as_float(uy & 0xFFFF0000u);
  float hz = __uint_as_float(uz & 0xFFFF0000u);
  float hw = __uint_as_float(uw & 0xFFFF0000u);
  hi.x = (ux >> 16) | (uy & 0xFFFF0000u);   // [x_bf16 | y_bf16]
  hi.y = (uz >> 16) | (uw & 0xFFFF0000u);
  unsigned lx = __float_as_uint(f.x - hx);
  unsigned ly = __float_as_uint(f.y - hy);
  unsigned lz = __float_as_uint(f.z - hz);
  unsigned lw = __float_as_uint(f.w - hw);
  lo.x = (lx >> 16) | (ly & 0xFFFF0000u);
  lo.y = (lz >> 16) | (lw & 0xFFFF0000u);
}

// One wave per row (4 rows/block): sq norms, align part, and zero-init S0/S1.
__global__ __launch_bounds__(256) void rownorm_align(
    const float* __restrict__ v0, const float* __restrict__ v1,
    float* __restrict__ sq0, float* __restrict__ sq1,
    float* __restrict__ S0, float* __restrict__ S1,
    float* __restrict__ align_part) {
  const int lane = threadIdx.x & 63;
  const int w = threadIdx.x >> 6;
  const int row = blockIdx.x * 4 + w;
  const float4 a = *(const float4*)(v0 + (size_t)row * D_DIM + lane * 4);
  const float4 b = *(const float4*)(v1 + (size_t)row * D_DIM + lane * 4);
  float s0 = a.x * a.x + a.y * a.y + a.z * a.z + a.w * a.w;
  float s1 = b.x * b.x + b.y * b.y + b.z * b.z + b.w * b.w;
  float dx = a.x - b.x, dy = a.y - b.y, dz = a.z - b.z, dw = a.w - b.w;
  float s2 = dx * dx + dy * dy + dz * dz + dw * dw;
  #pragma unroll
  for (int off = 1; off < 64; off <<= 1) {
    s0 += __shfl_xor(s0, off, 64);
    s1 += __shfl_xor(s1, off, 64);
    s2 += __shfl_xor(s2, off, 64);
  }
  if (lane == 0) {
    sq0[row] = s0;
    sq1[row] = s1;
    align_part[row] = sqrtf(s2);
    S0[row] = 0.0f;
    S1[row] = 0.0f;
  }
}

// 128x128 tile of the NxN distance matrix per block; grid.z selects the view.
// 4 waves (2x2), each wave 4x4 MFMA tiles of 16x16, 3 mfma per tile (hi/lo split).
// LDS holds hi+lo planes of A(128xBK32) and B(128x32) in MFMA-fragment order so
// fragment reads are 64-lane-contiguous ds_read_b128.
__global__ __launch_bounds__(256) void entropy_tile(
    const float* __restrict__ v0, const float* __restrict__ v1,
    const float* __restrict__ sq0, const float* __restrict__ sq1,
    float* __restrict__ S0, float* __restrict__ S1) {
  const float* __restrict__ z  = blockIdx.z ? v1 : v0;
  const float* __restrict__ sq = blockIdx.z ? sq1 : sq0;
  float* __restrict__ S        = blockIdx.z ? S1 : S0;

  __shared__ uint4 sAhi[512], sAlo[512], sBhi[512], sBlo[512];  // 8 KB each

  const int t = threadIdx.x;
  const int lane = t & 63;
  const int w = t >> 6;
  const int wi = w >> 1, wj = w & 1;       // 2x2 waves over the 128x128 tile
  const int quad = lane >> 4, l15 = lane & 15;
  const int i0 = blockIdx.x * 128, j0 = blockIdx.y * 128;

  f32x4 acc[4][4];
  #pragma unroll
  for (int m = 0; m < 4; ++m)
    #pragma unroll
    for (int n = 0; n < 4; ++n)
      acc[m][n] = (f32x4){0.f, 0.f, 0.f, 0.f};

  for (int k0 = 0; k0 < D_DIM; k0 += 32) {
    // Stage: 2 tiles x 128 rows x 32 k fp32 -> hi/lo bf16 planes.
    // thread t pass p: float4 index a = t + p*256; row r = a>>3, kq = a&7.
    // LDS fragment slot: 16B chunk (mt*4 + q)*16 + m holds A[mt*16+m][q*8..q*8+7].
    #pragma unroll
    for (int p = 0; p < 4; ++p) {
      const int aidx = t + p * 256;
      const int r = aidx >> 3, kq = aidx & 7;
      const float4 fa = *(const float4*)(z + (size_t)(i0 + r) * D_DIM + k0 + kq * 4);
      const float4 fb = *(const float4*)(z + (size_t)(j0 + r) * D_DIM + k0 + kq * 4);
      uint2 ha, la, hb, lb;
      split_pack(fa, ha, la);
      split_pack(fb, hb, lb);
      const int slot = ((((r >> 4) * 4 + (kq >> 1)) * 16 + (r & 15)) << 1) | (kq & 1);
      ((uint2*)sAhi)[slot] = ha;
      ((uint2*)sAlo)[slot] = la;
      ((uint2*)sBhi)[slot] = hb;
      ((uint2*)sBlo)[slot] = lb;
    }
    __syncthreads();

    bf16x8 ah[4], al[4], bh[4], bl[4];
    #pragma unroll
    for (int m = 0; m < 4; ++m) {
      const int mt = wi * 4 + m;
      ah[m] = ((const bf16x8*)sAhi)[mt * 64 + lane];
      al[m] = ((const bf16x8*)sAlo)[mt * 64 + lane];
    }
    #pragma unroll
    for (int n = 0; n < 4; ++n) {
      const int nt = wj * 4 + n;
      bh[n] = ((const bf16x8*)sBhi)[nt * 64 + lane];
      bl[n] = ((const bf16x8*)sBlo)[nt * 64 + lane];
    }

    #pragma unroll
    for (int m = 0; m < 4; ++m)
      #pragma unroll
      for (int n = 0; n < 4; ++n) {
        acc[m][n] = __builtin_amdgcn_mfma_f32_16x16x32_bf16(ah[m], bh[n], acc[m][n], 0, 0, 0);
        acc[m][n] = __builtin_amdgcn_mfma_f32_16x16x32_bf16(ah[m], bl[n], acc[m][n], 0, 0, 0);
        acc[m][n] = __builtin_amdgcn_mfma_f32_16x16x32_bf16(al[m], bh[n], acc[m][n], 0, 0, 0);
      }
    __syncthreads();
  }

  // Epilogue: C/D layout col=l15, row=quad*4+reg. d2 -> dist -> exp, diag masked,
  // shuffle-reduce over the 16 lanes of each quad-row, 1 atomic per row-fragment.
  float sj[4];
  #pragma unroll
  for (int n = 0; n < 4; ++n) sj[n] = sq[j0 + wj * 64 + n * 16 + l15];

  #pragma unroll
  for (int m = 0; m < 4; ++m) {
    #pragma unroll
    for (int r = 0; r < 4; ++r) {
      const int ib = wi * 64 + m * 16 + quad * 4 + r;
      const float si = sq[i0 + ib];
      float p = 0.0f;
      #pragma unroll
      for (int n = 0; n < 4; ++n) {
        const int jb = wj * 64 + n * 16 + l15;
        const float d2 = si + sj[n] - 2.0f * acc[m][n][r];
        float dist = sqrtf(fmaxf(d2, 0.0f));
        dist = fmaxf(dist, 1e-12f);
        const float e = __expf(-dist);
        p += (i0 + ib == j0 + jb) ? 0.0f : e;
      }
      p += __shfl_xor(p, 1, 16);
      p += __shfl_xor(p, 2, 16);
      p += __shfl_xor(p, 4, 16);
      p += __shfl_xor(p, 8, 16);
      if (l15 == 0) atomicAdd(&S[i0 + ib], p);
    }
  }
}

__global__ void finalize_kernel(const float* __restrict__ S0, const float* __restrict__ S1,
                                const float* __restrict__ align_part, float* __restrict__ out,
                                int n) {
  __shared__ double sh[256], sh2[256];
  const int t = threadIdx.x;
  double s = 0.0, al = 0.0;
  for (int i = t; i < n; i += 256) {
    s += (double)__logf(S0[i]) + (double)__logf(S1[i]);
    al += (double)align_part[i];
  }
  sh[t] = s;
  sh2[t] = al;
  __syncthreads();
  for (int off = 128; off > 0; off >>= 1) {
    if (t < off) { sh[t] += sh[t + off]; sh2[t] += sh2[t + off]; }
    __syncthreads();
  }
  if (t == 0) {
    double align = sh2[0] / (double)n;
    double entropy = 0.5 * sh[0] / (double)n - log((double)(n - 1));
    out[0] = (float)(align + entropy);
  }
}

extern "C" void kernel_launch(void* const* d_in, const int* in_sizes, int n_in,
                              void* d_out, int out_size, void* d_ws, size_t ws_size,
                              hipStream_t stream) {
  const float* v0 = (const float*)d_in[0];
  const float* v1 = (const float*)d_in[1];
  float* out = (float*)d_out;
  const int n = in_sizes[0] / D_DIM;  // 8192

  float* ws         = (float*)d_ws;
  float* sq0        = ws;
  float* sq1        = ws + n;
  float* S0         = ws + 2 * n;
  float* S1         = ws + 3 * n;
  float* align_part = ws + 4 * n;

  rownorm_align<<<n / 4, 256, 0, stream>>>(v0, v1, sq0, sq1, S0, S1, align_part);

  dim3 grid(n / 128, n / 128, 2);
  entropy_tile<<<grid, 256, 0, stream>>>(v0, v1, sq0, sq1, S0, S1);

  finalize_kernel<<<1, 256, 0, stream>>>(S0, S1, align_part, out, n);
}

// Round 3
// 225.036 us; speedup vs baseline: 5.2782x; 2.1506x over previous
//
#include <hip/hip_runtime.h>
#include <math.h>

// N=8192 rows, D=256, fp32 in, scalar fp32 out.
// out = mean_i ||v0_i-v1_i|| + 0.5*(mean_i log S0_i + mean_i log S1_i) - log(N-1)
// S_i = sum_{j!=i} exp(-sqrt(max(sq_i+sq_j-2*z_i.z_j,0)))
//
// Round 3: single bf16 MFMA (RTN rounding; error on dist ~1e-3 random, ~1e-5 on
// output -- threshold 7.6e-3), packed fragment-ordered bf16 planes precomputed
// once, global_load_lds staging, triangular (symmetric) block grid.

#define D_DIM 256
#define NB 64                 // 8192/128 panels
#define NBLK 2080             // NB*(NB+1)/2

typedef short bf16x8 __attribute__((ext_vector_type(8)));
typedef float f32x4 __attribute__((ext_vector_type(4)));
typedef unsigned int u32;
#define AS1 __attribute__((address_space(1)))
#define AS3 __attribute__((address_space(3)))

__device__ inline void load_lds16(const void* g, void* l) {
  __builtin_amdgcn_global_load_lds((const AS1 u32*)g, (AS3 u32*)l, 16, 0, 0);
}

__device__ inline unsigned bf16_rtn(float f) {
  unsigned u = __float_as_uint(f);
  return (u + 0x7FFFu + ((u >> 16) & 1u)) >> 16;
}

// One wave per row: sq norms, align part, zero S, and emit packed bf16 planes.
// Packed layout (per plane), bf16 element index:
//   ((R*8 + s)*64 + q*16 + rr)*8 + j   for element (row = R*16+rr, k = s*32+q*8+j)
// i.e. for each (16-row group R, k-step s) a contiguous 1 KB block in exactly the
// order a wave's 64 lanes (lane = q*16+rr) consume it as an MFMA fragment.
__global__ __launch_bounds__(256) void prep(
    const float* __restrict__ v0, const float* __restrict__ v1,
    unsigned short* __restrict__ ph0, unsigned short* __restrict__ ph1,
    float* __restrict__ sq0, float* __restrict__ sq1,
    float* __restrict__ S0, float* __restrict__ S1,
    float* __restrict__ align_part) {
  const int lane = threadIdx.x & 63;
  const int w = threadIdx.x >> 6;
  const int row = blockIdx.x * 4 + w;
  const float4 a = *(const float4*)(v0 + (size_t)row * D_DIM + lane * 4);
  const float4 b = *(const float4*)(v1 + (size_t)row * D_DIM + lane * 4);

  const int R = row >> 4, rr = row & 15;
  const int c = lane >> 1, s = c >> 2, q = c & 3;
  const size_t off = ((size_t)((R * 8 + s) * 64 + q * 16 + rr)) * 8 + (lane & 1) * 4;
  uint2 pa, pb;
  pa.x = bf16_rtn(a.x) | (bf16_rtn(a.y) << 16);
  pa.y = bf16_rtn(a.z) | (bf16_rtn(a.w) << 16);
  pb.x = bf16_rtn(b.x) | (bf16_rtn(b.y) << 16);
  pb.y = bf16_rtn(b.z) | (bf16_rtn(b.w) << 16);
  *(uint2*)(ph0 + off) = pa;
  *(uint2*)(ph1 + off) = pb;

  float s0 = a.x * a.x + a.y * a.y + a.z * a.z + a.w * a.w;
  float s1 = b.x * b.x + b.y * b.y + b.z * b.z + b.w * b.w;
  float dx = a.x - b.x, dy = a.y - b.y, dz = a.z - b.z, dw = a.w - b.w;
  float s2 = dx * dx + dy * dy + dz * dz + dw * dw;
  #pragma unroll
  for (int o = 1; o < 64; o <<= 1) {
    s0 += __shfl_xor(s0, o, 64);
    s1 += __shfl_xor(s1, o, 64);
    s2 += __shfl_xor(s2, o, 64);
  }
  if (lane == 0) {
    sq0[row] = s0;
    sq1[row] = s1;
    align_part[row] = sqrtf(s2);
    S0[row] = 0.0f;
    S1[row] = 0.0f;
  }
}

// Triangular 128x128 tiles (bi <= bj); grid.y = view. 4 waves in 2x2, each wave
// 4x4 tiles of mfma_f32_16x16x32_bf16. Staging: global_load_lds 16B, fully
// coalesced from the packed planes, LDS already in fragment order.
__global__ __launch_bounds__(256) void entropy_tile(
    const unsigned short* __restrict__ ph0, const unsigned short* __restrict__ ph1,
    const float* __restrict__ sq0, const float* __restrict__ sq1,
    float* __restrict__ S0, float* __restrict__ S1) {
  const unsigned short* __restrict__ ph = blockIdx.y ? ph1 : ph0;
  const float* __restrict__ sq = blockIdx.y ? sq1 : sq0;
  float* __restrict__ S        = blockIdx.y ? S1 : S0;

  // decode linear block -> (bi, bj), bi <= bj, row-major upper triangle
  const int b = blockIdx.x;
  int bi = (int)((129.0 - sqrt(16641.0 - 8.0 * (double)b)) * 0.5);
  while ((bi + 1) * NB - ((bi + 1) * bi) / 2 <= b) ++bi;
  while (bi * NB - (bi * (bi - 1)) / 2 > b) --bi;
  const int bj = bi + (b - (bi * NB - (bi * (bi - 1)) / 2));
  const bool diag = (bi == bj);

  __shared__ unsigned short sA[4096];  // 8 KB: 8 R-groups x 1 KB fragment blocks
  __shared__ unsigned short sB[4096];

  const int t = threadIdx.x, lane = t & 63, w = t >> 6;
  const int wi = w >> 1, wj = w & 1;
  const int quad = lane >> 4, l15 = lane & 15;
  const int i0 = bi * 128, j0 = bj * 128;

  f32x4 acc[4][4];
  #pragma unroll
  for (int m = 0; m < 4; ++m)
    #pragma unroll
    for (int n = 0; n < 4; ++n)
      acc[m][n] = (f32x4){0.f, 0.f, 0.f, 0.f};

  for (int s = 0; s < 8; ++s) {
    // 16 x 1KB wave-loads: waves 0,1 -> A groups 0..7; waves 2,3 -> B groups 0..7
    #pragma unroll
    for (int u = 0; u < 4; ++u) {
      const int l = w * 4 + u;
      const int g = l & 7;
      const int Rb = (l < 8) ? bi * 8 : bj * 8;
      unsigned short* dst = ((l < 8) ? sA : sB) + g * 512;
      const unsigned short* src = ph + ((size_t)((Rb + g) * 8 + s)) * 512 + lane * 8;
      load_lds16(src, dst);
    }
    __syncthreads();  // drains vmcnt (global_load_lds) before fragment reads

    bf16x8 ah[4], bh[4];
    #pragma unroll
    for (int m = 0; m < 4; ++m) ah[m] = ((const bf16x8*)sA)[(wi * 4 + m) * 64 + lane];
    #pragma unroll
    for (int n = 0; n < 4; ++n) bh[n] = ((const bf16x8*)sB)[(wj * 4 + n) * 64 + lane];

    #pragma unroll
    for (int m = 0; m < 4; ++m)
      #pragma unroll
      for (int n = 0; n < 4; ++n)
        acc[m][n] = __builtin_amdgcn_mfma_f32_16x16x32_bf16(ah[m], bh[n], acc[m][n], 0, 0, 0);
    __syncthreads();  // all reads done before next stage overwrites
  }

  // Epilogue. C/D layout: col = l15, row = quad*4+reg.
  float sj[4];
  #pragma unroll
  for (int n = 0; n < 4; ++n) sj[n] = sq[j0 + wj * 64 + n * 16 + l15];

  float csum[4] = {0.f, 0.f, 0.f, 0.f};
  #pragma unroll
  for (int m = 0; m < 4; ++m) {
    #pragma unroll
    for (int r = 0; r < 4; ++r) {
      const int gi = i0 + wi * 64 + m * 16 + quad * 4 + r;
      const float si = sq[gi];
      float p = 0.f;
      #pragma unroll
      for (int n = 0; n < 4; ++n) {
        const float d2 = fmaf(-2.0f, acc[m][n][r], si + sj[n]);
        const float dist = sqrtf(fmaxf(d2, 0.0f));
        float e = __expf(-dist);
        if (diag && gi == j0 + wj * 64 + n * 16 + l15) e = 0.f;
        p += e;
        csum[n] += e;
      }
      p += __shfl_xor(p, 1, 16);
      p += __shfl_xor(p, 2, 16);
      p += __shfl_xor(p, 4, 16);
      p += __shfl_xor(p, 8, 16);
      if (l15 == 0) atomicAdd(&S[gi], p);
    }
  }
  if (!diag) {
    // column sums -> symmetric contribution S[j] += sum_i exp(-d_ij)
    #pragma unroll
    for (int n = 0; n < 4; ++n) {
      float c2 = csum[n];
      c2 += __shfl_xor(c2, 16, 64);
      c2 += __shfl_xor(c2, 32, 64);
      if (quad == 0) atomicAdd(&S[j0 + wj * 64 + n * 16 + l15], c2);
    }
  }
}

__global__ void finalize_kernel(const float* __restrict__ S0, const float* __restrict__ S1,
                                const float* __restrict__ align_part, float* __restrict__ out,
                                int n) {
  __shared__ double sh[256], sh2[256];
  const int t = threadIdx.x;
  double s = 0.0, al = 0.0;
  for (int i = t; i < n; i += 256) {
    s += (double)__logf(S0[i]) + (double)__logf(S1[i]);
    al += (double)align_part[i];
  }
  sh[t] = s;
  sh2[t] = al;
  __syncthreads();
  for (int off = 128; off > 0; off >>= 1) {
    if (t < off) { sh[t] += sh[t + off]; sh2[t] += sh2[t + off]; }
    __syncthreads();
  }
  if (t == 0) {
    double align = sh2[0] / (double)n;
    double entropy = 0.5 * sh[0] / (double)n - log((double)(n - 1));
    out[0] = (float)(align + entropy);
  }
}

extern "C" void kernel_launch(void* const* d_in, const int* in_sizes, int n_in,
                              void* d_out, int out_size, void* d_ws, size_t ws_size,
                              hipStream_t stream) {
  const float* v0 = (const float*)d_in[0];
  const float* v1 = (const float*)d_in[1];
  float* out = (float*)d_out;
  const int n = in_sizes[0] / D_DIM;  // 8192

  float* ws         = (float*)d_ws;
  float* sq0        = ws;             // n f32
  float* sq1        = ws + n;
  float* S0         = ws + 2 * n;
  float* S1         = ws + 3 * n;
  float* align_part = ws + 4 * n;
  // packed bf16 planes, 16B-aligned (5n floats = 160 KB, multiple of 16B)
  unsigned short* ph0 = (unsigned short*)(ws + 5 * n);            // n*256 bf16 = 4 MB
  unsigned short* ph1 = ph0 + (size_t)n * D_DIM;                  // 4 MB

  prep<<<n / 4, 256, 0, stream>>>(v0, v1, ph0, ph1, sq0, sq1, S0, S1, align_part);

  dim3 grid(NBLK, 2);
  entropy_tile<<<grid, 256, 0, stream>>>(ph0, ph1, sq0, sq1, S0, S1);

  finalize_kernel<<<1, 256, 0, stream>>>(S0, S1, align_part, out, n);
}